// Round 1
// baseline (1642.524 us; speedup 1.0000x reference)
//
#include <hip/hip_runtime.h>
#include <math.h>

// Problem constants
#define NB    8
#define CIN   2048
#define CHID  256
#define NP    1024   // h*w = 32*32

// GEMM tile config (shared by all three matmul kernels)
#define BM 128
#define BN 128
#define BK 16
#define TM 8
#define TN 8
// 256 threads = 16x16 thread grid, each thread does 8x8 outputs

// ws layout (floats):
//   qk:  [4][NB][CHID][NP]  mats: 0=Q1(Wq1*f1) 1=K1(Wk1*f2) 2=Q2(Wq2*f2) 3=K2(Wk2*f1)
//   S :  [NB][NP(p)][NP(q)] one side at a time (scores', then attn' in place)
static const size_t QBUF_FLOATS = 4ull * NB * CHID * NP;   // 8,388,608
static const size_t SBUF_FLOATS = (size_t)NB * NP * NP;    // 8,388,608

// ---------------------------------------------------------------------------
// Projection: C[o][p] = sum_c W[o][c] * F[b][c][p] + bias[o]
// A = W (MxK row-major), B = F_b (KxN row-major)
// ---------------------------------------------------------------------------
__global__ __launch_bounds__(256) void proj_kernel(
    const float* __restrict__ f1, const float* __restrict__ f2,
    const float* __restrict__ Wq1, const float* __restrict__ bq1,
    const float* __restrict__ Wk1, const float* __restrict__ bk1,
    const float* __restrict__ Wq2, const float* __restrict__ bq2,
    const float* __restrict__ Wk2, const float* __restrict__ bk2,
    float* __restrict__ qk)
{
    const int z   = blockIdx.z;      // mat*NB + b
    const int mat = z >> 3;
    const int b   = z & 7;
    const float* W; const float* bias; const float* F;
    if      (mat == 0) { W = Wq1; bias = bq1; F = f1; }
    else if (mat == 1) { W = Wk1; bias = bk1; F = f2; }
    else if (mat == 2) { W = Wq2; bias = bq2; F = f2; }
    else               { W = Wk2; bias = bk2; F = f1; }
    F += (size_t)b * CIN * NP;
    float* C = qk + ((size_t)mat * NB + b) * CHID * NP;

    const int m0 = blockIdx.y * BM;   // over CHID (2 tiles)
    const int n0 = blockIdx.x * BN;   // over NP   (8 tiles)

    __shared__ float As[BK][BM + 4];  // k-major (transposed on store), padded
    __shared__ float Bs[BK][BN];

    const int tid = threadIdx.x;
    const int tm = tid >> 4;          // 0..15
    const int tn = tid & 15;          // 0..15

    float acc[TM][TN];
#pragma unroll
    for (int j = 0; j < TM; ++j)
#pragma unroll
        for (int i = 0; i < TN; ++i) acc[j][i] = 0.f;

    const int arow = tid >> 2;        // 0..63
    const int acol = (tid & 3) * 4;   // 0,4,8,12
    const int brow = tid >> 5;        // 0..7
    const int bcol = (tid & 31) * 4;  // 0..124

    for (int k0 = 0; k0 < CIN; k0 += BK) {
        // A tile: W[m0+row][k0+col], store transposed into As[k][m]
#pragma unroll
        for (int ps = 0; ps < 2; ++ps) {
            const int r = arow + ps * 64;
            const float4 v = *reinterpret_cast<const float4*>(
                &W[(size_t)(m0 + r) * CIN + k0 + acol]);
            As[acol + 0][r] = v.x;
            As[acol + 1][r] = v.y;
            As[acol + 2][r] = v.z;
            As[acol + 3][r] = v.w;
        }
        // B tile: F[k0+row][n0+col], natural layout
#pragma unroll
        for (int ps = 0; ps < 2; ++ps) {
            const int r = brow + ps * 8;
            *reinterpret_cast<float4*>(&Bs[r][bcol]) =
                *reinterpret_cast<const float4*>(&F[(size_t)(k0 + r) * NP + n0 + bcol]);
        }
        __syncthreads();

#pragma unroll
        for (int kk = 0; kk < BK; ++kk) {
            const float4 a0 = *reinterpret_cast<const float4*>(&As[kk][tm * TM]);
            const float4 a1 = *reinterpret_cast<const float4*>(&As[kk][tm * TM + 4]);
            const float4 b0 = *reinterpret_cast<const float4*>(&Bs[kk][tn * TN]);
            const float4 b1 = *reinterpret_cast<const float4*>(&Bs[kk][tn * TN + 4]);
            const float a[TM] = {a0.x, a0.y, a0.z, a0.w, a1.x, a1.y, a1.z, a1.w};
            const float bb[TN] = {b0.x, b0.y, b0.z, b0.w, b1.x, b1.y, b1.z, b1.w};
#pragma unroll
            for (int j = 0; j < TM; ++j)
#pragma unroll
                for (int i = 0; i < TN; ++i) acc[j][i] += a[j] * bb[i];
        }
        __syncthreads();
    }

    // epilogue + bias
#pragma unroll
    for (int j = 0; j < TM; ++j) {
        const int row = m0 + tm * TM + j;
        const float bv = bias[row];
        float4 o0 = {acc[j][0] + bv, acc[j][1] + bv, acc[j][2] + bv, acc[j][3] + bv};
        float4 o1 = {acc[j][4] + bv, acc[j][5] + bv, acc[j][6] + bv, acc[j][7] + bv};
        float* dst = &C[(size_t)row * NP + n0 + tn * TN];
        *reinterpret_cast<float4*>(dst)     = o0;
        *reinterpret_cast<float4*>(dst + 4) = o1;
    }
}

// ---------------------------------------------------------------------------
// Scores (transposed): S'[p][q] = sum_o K[o][p] * Q[o][q]
// Both operands K-major (o-major) -> load like B tiles, no transpose needed.
// ---------------------------------------------------------------------------
__global__ __launch_bounds__(256) void scores_kernel(
    const float* __restrict__ qk, float* __restrict__ S, int side)
{
    const int b = blockIdx.z;
    const float* Q = qk + ((size_t)(side * 2 + 0) * NB + b) * CHID * NP;
    const float* K = qk + ((size_t)(side * 2 + 1) * NB + b) * CHID * NP;
    float* Sb = S + (size_t)b * NP * NP;

    const int m0 = blockIdx.y * BM;   // p
    const int n0 = blockIdx.x * BN;   // q

    __shared__ float As[BK][BN];      // K tile [o][p]
    __shared__ float Bs[BK][BN];      // Q tile [o][q]

    const int tid = threadIdx.x;
    const int tm = tid >> 4;
    const int tn = tid & 15;

    float acc[TM][TN];
#pragma unroll
    for (int j = 0; j < TM; ++j)
#pragma unroll
        for (int i = 0; i < TN; ++i) acc[j][i] = 0.f;

    const int brow = tid >> 5;        // 0..7
    const int bcol = (tid & 31) * 4;  // 0..124

    for (int k0 = 0; k0 < CHID; k0 += BK) {
#pragma unroll
        for (int ps = 0; ps < 2; ++ps) {
            const int r = brow + ps * 8;
            *reinterpret_cast<float4*>(&As[r][bcol]) =
                *reinterpret_cast<const float4*>(&K[(size_t)(k0 + r) * NP + m0 + bcol]);
            *reinterpret_cast<float4*>(&Bs[r][bcol]) =
                *reinterpret_cast<const float4*>(&Q[(size_t)(k0 + r) * NP + n0 + bcol]);
        }
        __syncthreads();

#pragma unroll
        for (int kk = 0; kk < BK; ++kk) {
            const float4 a0 = *reinterpret_cast<const float4*>(&As[kk][tm * TM]);
            const float4 a1 = *reinterpret_cast<const float4*>(&As[kk][tm * TM + 4]);
            const float4 b0 = *reinterpret_cast<const float4*>(&Bs[kk][tn * TN]);
            const float4 b1 = *reinterpret_cast<const float4*>(&Bs[kk][tn * TN + 4]);
            const float a[TM] = {a0.x, a0.y, a0.z, a0.w, a1.x, a1.y, a1.z, a1.w};
            const float bb[TN] = {b0.x, b0.y, b0.z, b0.w, b1.x, b1.y, b1.z, b1.w};
#pragma unroll
            for (int j = 0; j < TM; ++j)
#pragma unroll
                for (int i = 0; i < TN; ++i) acc[j][i] += a[j] * bb[i];
        }
        __syncthreads();
    }

#pragma unroll
    for (int j = 0; j < TM; ++j) {
        const int row = m0 + tm * TM + j;   // p
        float* dst = &Sb[(size_t)row * NP + n0 + tn * TN];
        float4 o0 = {acc[j][0], acc[j][1], acc[j][2], acc[j][3]};
        float4 o1 = {acc[j][4], acc[j][5], acc[j][6], acc[j][7]};
        *reinterpret_cast<float4*>(dst)     = o0;
        *reinterpret_cast<float4*>(dst + 4) = o1;
    }
}

// ---------------------------------------------------------------------------
// Column softmax over p (rows of S'), per column q. In place.
// Block: 64 q-columns x 4 p-groups of 256 rows.
// ---------------------------------------------------------------------------
__global__ __launch_bounds__(256) void softmax_kernel(float* __restrict__ S)
{
    const int b  = blockIdx.y;
    const int q0 = blockIdx.x * 64;
    float* Sb = S + (size_t)b * NP * NP;

    const int qi = threadIdx.x & 63;
    const int pg = threadIdx.x >> 6;   // 0..3
    const int q  = q0 + qi;

    __shared__ float red[4][64];

    float m = -INFINITY;
    for (int i = 0; i < 256; ++i)
        m = fmaxf(m, Sb[(size_t)(pg * 256 + i) * NP + q]);
    red[pg][qi] = m;
    __syncthreads();
    const float mm = fmaxf(fmaxf(red[0][qi], red[1][qi]),
                           fmaxf(red[2][qi], red[3][qi]));
    __syncthreads();

    float s = 0.f;
    for (int i = 0; i < 256; ++i)
        s += __expf(Sb[(size_t)(pg * 256 + i) * NP + q] - mm);
    red[pg][qi] = s;
    __syncthreads();
    const float inv = 1.0f / (red[0][qi] + red[1][qi] + red[2][qi] + red[3][qi]);

    for (int i = 0; i < 256; ++i) {
        const size_t idx = (size_t)(pg * 256 + i) * NP + q;
        Sb[idx] = __expf(Sb[idx] - mm) * inv;
    }
}

// ---------------------------------------------------------------------------
// Attended: out[c][q] = sum_p V[c][p] * attn'[p][q]
// A = V (MxK row-major, transposed on LDS store), B = attn' (KxN natural)
// ---------------------------------------------------------------------------
__global__ __launch_bounds__(256) void attended_kernel(
    const float* __restrict__ V, const float* __restrict__ S,
    float* __restrict__ out)
{
    const int b = blockIdx.z;
    const float* Vb = V + (size_t)b * CIN * NP;
    const float* Sb = S + (size_t)b * NP * NP;
    float* Ob = out + (size_t)b * CIN * NP;

    const int m0 = blockIdx.y * BM;   // c over 2048 (16 tiles)
    const int n0 = blockIdx.x * BN;   // q over 1024 (8 tiles)

    __shared__ float As[BK][BM + 4];  // V^T tile [p][c]
    __shared__ float Bs[BK][BN];      // attn' [p][q]

    const int tid = threadIdx.x;
    const int tm = tid >> 4;
    const int tn = tid & 15;

    float acc[TM][TN];
#pragma unroll
    for (int j = 0; j < TM; ++j)
#pragma unroll
        for (int i = 0; i < TN; ++i) acc[j][i] = 0.f;

    const int arow = tid >> 2;        // 0..63
    const int acol = (tid & 3) * 4;   // 0,4,8,12
    const int brow = tid >> 5;        // 0..7
    const int bcol = (tid & 31) * 4;  // 0..124

    for (int k0 = 0; k0 < NP; k0 += BK) {
#pragma unroll
        for (int ps = 0; ps < 2; ++ps) {
            const int r = arow + ps * 64;
            const float4 v = *reinterpret_cast<const float4*>(
                &Vb[(size_t)(m0 + r) * NP + k0 + acol]);
            As[acol + 0][r] = v.x;
            As[acol + 1][r] = v.y;
            As[acol + 2][r] = v.z;
            As[acol + 3][r] = v.w;
        }
#pragma unroll
        for (int ps = 0; ps < 2; ++ps) {
            const int r = brow + ps * 8;
            *reinterpret_cast<float4*>(&Bs[r][bcol]) =
                *reinterpret_cast<const float4*>(&Sb[(size_t)(k0 + r) * NP + n0 + bcol]);
        }
        __syncthreads();

#pragma unroll
        for (int kk = 0; kk < BK; ++kk) {
            const float4 a0 = *reinterpret_cast<const float4*>(&As[kk][tm * TM]);
            const float4 a1 = *reinterpret_cast<const float4*>(&As[kk][tm * TM + 4]);
            const float4 b0 = *reinterpret_cast<const float4*>(&Bs[kk][tn * TN]);
            const float4 b1 = *reinterpret_cast<const float4*>(&Bs[kk][tn * TN + 4]);
            const float a[TM] = {a0.x, a0.y, a0.z, a0.w, a1.x, a1.y, a1.z, a1.w};
            const float bb[TN] = {b0.x, b0.y, b0.z, b0.w, b1.x, b1.y, b1.z, b1.w};
#pragma unroll
            for (int j = 0; j < TM; ++j)
#pragma unroll
                for (int i = 0; i < TN; ++i) acc[j][i] += a[j] * bb[i];
        }
        __syncthreads();
    }

#pragma unroll
    for (int j = 0; j < TM; ++j) {
        const int row = m0 + tm * TM + j;   // c
        float* dst = &Ob[(size_t)row * NP + n0 + tn * TN];
        float4 o0 = {acc[j][0], acc[j][1], acc[j][2], acc[j][3]};
        float4 o1 = {acc[j][4], acc[j][5], acc[j][6], acc[j][7]};
        *reinterpret_cast<float4*>(dst)     = o0;
        *reinterpret_cast<float4*>(dst + 4) = o1;
    }
}

// ---------------------------------------------------------------------------
extern "C" void kernel_launch(void* const* d_in, const int* in_sizes, int n_in,
                              void* d_out, int out_size, void* d_ws, size_t ws_size,
                              hipStream_t stream)
{
    const float* f1  = (const float*)d_in[0];
    const float* f2  = (const float*)d_in[1];
    const float* Wq1 = (const float*)d_in[2];
    const float* bq1 = (const float*)d_in[3];
    const float* Wk1 = (const float*)d_in[4];
    const float* bk1 = (const float*)d_in[5];
    const float* Wq2 = (const float*)d_in[6];
    const float* bq2 = (const float*)d_in[7];
    const float* Wk2 = (const float*)d_in[8];
    const float* bk2 = (const float*)d_in[9];
    float* out = (float*)d_out;

    float* qk = (float*)d_ws;
    float* S  = qk + QBUF_FLOATS;

    const dim3 blk(256);

    // All four projections: Q1,K1,Q2,K2
    proj_kernel<<<dim3(NP / BN, CHID / BM, 4 * NB), blk, 0, stream>>>(
        f1, f2, Wq1, bq1, Wk1, bk1, Wq2, bq2, Wk2, bk2, qk);

    for (int side = 0; side < 2; ++side) {
        scores_kernel<<<dim3(NP / BN, NP / BM, NB), blk, 0, stream>>>(qk, S, side);
        softmax_kernel<<<dim3(NP / 64, NB), blk, 0, stream>>>(S);
        const float* V = (side == 0) ? f2 : f1;
        float* o = out + (size_t)side * NB * CIN * NP;
        attended_kernel<<<dim3(NP / BN, CIN / BM, NB), blk, 0, stream>>>(V, S, o);
    }
}

// Round 3
// 510.280 us; speedup vs baseline: 3.2189x; 3.2189x over previous
//
#include <hip/hip_runtime.h>
#include <math.h>

#define NB   8
#define CIN  2048
#define CHID 256
#define NP   1024

typedef _Float16 f16;
typedef _Float16 f16x8 __attribute__((ext_vector_type(8)));
typedef float    f32x4 __attribute__((ext_vector_type(4)));

// ---------------------------------------------------------------------------
// ws layout (bytes):
//   [0, 67108864)           : Ft f16 [2][NB][NP][CIN]   (convert+proj phase)
//       reused after proj:    S  f32 [NB][NP][NP] at 0        (33,554,432)
//                             attn f16 [NB][NP][NP] at 33554432 (16,777,216)
//   [67108864, 83886080)    : QK f16 [4][NB][NP][CHID]  (Q1,K1,Q2,K2, [p][o])
//   [83886080, 88080384)    : Wf16 [4][CHID][CIN]
// peak ws = 88,080,384 B
// ---------------------------------------------------------------------------

// Stage a [128 outer][64 k] f16 tile into LDS with XOR-swizzled 16B slots.
__device__ inline void stage_f16(const f16* __restrict__ g, int stride,
                                 int outer0, int k0, f16* lds, int t)
{
    const int r0 = t >> 3;          // 0..31
    const int sl = t & 7;           // 16B slot within 128B row
#pragma unroll
    for (int it = 0; it < 4; ++it) {
        const int row = r0 + it * 32;
        const int4 v = *reinterpret_cast<const int4*>(
            &g[(size_t)(outer0 + row) * stride + k0 + sl * 8]);
        const int byte = (row * 128 + sl * 16) ^ ((row & 7) << 4);
        *reinterpret_cast<int4*>(reinterpret_cast<char*>(lds) + byte) = v;
    }
}

// Read one MFMA fragment (8 contiguous k at one row) from swizzled LDS tile.
__device__ inline f16x8 ldsfrag(const f16* lds, int row, int kbyte)
{
    const char* p = reinterpret_cast<const char*>(lds) +
                    ((row * 128 + kbyte) ^ ((row & 7) << 4));
    return *reinterpret_cast<const f16x8*>(p);
}

// ---------------------------------------------------------------------------
// convert_W: 4 weight mats fp32 [CHID][CIN] -> f16, same layout
// ---------------------------------------------------------------------------
__global__ __launch_bounds__(256) void convert_W(
    const float* __restrict__ Wq1, const float* __restrict__ Wk1,
    const float* __restrict__ Wq2, const float* __restrict__ Wk2,
    f16* __restrict__ Wf)
{
    const int n4 = CHID * CIN / 4;               // float4 chunks per mat
    const int i = blockIdx.x * 256 + threadIdx.x; // 0 .. 4*n4-1
    const int mat = i / n4;
    const int j = i - mat * n4;
    const float* W = (mat == 0) ? Wq1 : (mat == 1) ? Wk1 : (mat == 2) ? Wq2 : Wk2;
    const float4 v = *reinterpret_cast<const float4*>(&W[(size_t)j * 4]);
    union { f16 h[4]; uint2 u; } o;
    o.h[0] = (f16)v.x; o.h[1] = (f16)v.y; o.h[2] = (f16)v.z; o.h[3] = (f16)v.w;
    *reinterpret_cast<uint2*>(&Wf[(size_t)i * 4]) = o.u;
}

// ---------------------------------------------------------------------------
// convert_F: F fp32 [b][c][p] -> Ft f16 [feat][b][p][c] (transposed per batch)
// 64x64 tiles through LDS.
// ---------------------------------------------------------------------------
__global__ __launch_bounds__(256) void convert_F(
    const float* __restrict__ f1, const float* __restrict__ f2,
    f16* __restrict__ Ft)
{
    const int z = blockIdx.z;               // feat*NB + b
    const int feat = z >> 3, b = z & 7;
    const float* F = (feat ? f2 : f1) + (size_t)b * CIN * NP;
    f16* T = Ft + ((size_t)feat * NB + b) * NP * CIN;
    const int c0 = blockIdx.y * 64, p0 = blockIdx.x * 64;

    __shared__ float tile[64][65];
    const int t = threadIdx.x;
    const int r = t >> 4, c4 = (t & 15) * 4;

#pragma unroll
    for (int it = 0; it < 4; ++it) {
        const int cr = r + it * 16;
        const float4 v = *reinterpret_cast<const float4*>(
            &F[(size_t)(c0 + cr) * NP + p0 + c4]);
        tile[cr][c4 + 0] = v.x;
        tile[cr][c4 + 1] = v.y;
        tile[cr][c4 + 2] = v.z;
        tile[cr][c4 + 3] = v.w;
    }
    __syncthreads();
#pragma unroll
    for (int it = 0; it < 4; ++it) {
        const int pr = r + it * 16;
        union { f16 h[4]; uint2 u; } o;
        o.h[0] = (f16)tile[c4 + 0][pr];
        o.h[1] = (f16)tile[c4 + 1][pr];
        o.h[2] = (f16)tile[c4 + 2][pr];
        o.h[3] = (f16)tile[c4 + 3][pr];
        *reinterpret_cast<uint2*>(&T[(size_t)(p0 + pr) * CIN + c0 + c4]) = o.u;
    }
}

// ---------------------------------------------------------------------------
// proj: QK[mat][b][p][o] = f16( sum_c W[o][c]*F[c][p] + bias[o] )
// A = Wf16 [o][c], B = Ft [p][c]. 128x128 tile, K-step 64, 4 waves 2x2.
// ---------------------------------------------------------------------------
__global__ __launch_bounds__(256) void proj_mfma(
    const f16* __restrict__ Wf, const f16* __restrict__ Ft,
    const float* __restrict__ bq1, const float* __restrict__ bk1,
    const float* __restrict__ bq2, const float* __restrict__ bk2,
    f16* __restrict__ QK)
{
    const int z = blockIdx.z;          // mat*NB + b
    const int mat = z >> 3, b = z & 7;
    const f16* A = Wf + (size_t)mat * CHID * CIN;
    const int feat = (mat == 0 || mat == 3) ? 0 : 1;  // Q1:f1 K1:f2 Q2:f2 K2:f1
    const f16* B = Ft + ((size_t)feat * NB + b) * NP * CIN;
    const float* bias = (mat == 0) ? bq1 : (mat == 1) ? bk1 : (mat == 2) ? bq2 : bk2;
    f16* C = QK + ((size_t)mat * NB + b) * NP * CHID;   // [p][o]

    const int m0 = blockIdx.y * 128;   // o
    const int n0 = blockIdx.x * 128;   // p

    __shared__ __align__(16) f16 As[128 * 64];
    __shared__ __align__(16) f16 Bs[128 * 64];

    const int t = threadIdx.x, lane = t & 63, w = t >> 6;
    const int wm = w >> 1, wn = w & 1;

    f32x4 acc[4][4];
#pragma unroll
    for (int i = 0; i < 4; ++i)
#pragma unroll
        for (int j = 0; j < 4; ++j) acc[i][j] = (f32x4){0.f, 0.f, 0.f, 0.f};

    for (int k0 = 0; k0 < CIN; k0 += 64) {
        stage_f16(A, CIN, m0, k0, As, t);
        stage_f16(B, CIN, n0, k0, Bs, t);
        __syncthreads();
#pragma unroll
        for (int kh = 0; kh < 2; ++kh) {
            f16x8 a[4], bb[4];
#pragma unroll
            for (int fm = 0; fm < 4; ++fm)
                a[fm] = ldsfrag(As, wm * 64 + fm * 16 + (lane & 15),
                                kh * 64 + (lane >> 4) * 16);
#pragma unroll
            for (int fn = 0; fn < 4; ++fn)
                bb[fn] = ldsfrag(Bs, wn * 64 + fn * 16 + (lane & 15),
                                 kh * 64 + (lane >> 4) * 16);
#pragma unroll
            for (int fm = 0; fm < 4; ++fm)
#pragma unroll
                for (int fn = 0; fn < 4; ++fn)
                    acc[fm][fn] = __builtin_amdgcn_mfma_f32_16x16x32_f16(
                        a[fm], bb[fn], acc[fm][fn], 0, 0, 0);
        }
        __syncthreads();
    }

    const int lo4 = (lane >> 4) * 4, lp = lane & 15;
#pragma unroll
    for (int fm = 0; fm < 4; ++fm) {
        const int obase = m0 + wm * 64 + fm * 16 + lo4;
        const float4 b4 = *reinterpret_cast<const float4*>(&bias[obase]);
#pragma unroll
        for (int fn = 0; fn < 4; ++fn) {
            const int p = n0 + wn * 64 + fn * 16 + lp;
            union { f16 h[4]; uint2 u; } o;
            o.h[0] = (f16)(acc[fm][fn][0] + b4.x);
            o.h[1] = (f16)(acc[fm][fn][1] + b4.y);
            o.h[2] = (f16)(acc[fm][fn][2] + b4.z);
            o.h[3] = (f16)(acc[fm][fn][3] + b4.w);
            *reinterpret_cast<uint2*>(&C[(size_t)p * CHID + obase]) = o.u;
        }
    }
}

// ---------------------------------------------------------------------------
// scores: S[q][p] = sum_o Q[q][o]*K[p][o]   (fp32 logits)
// ---------------------------------------------------------------------------
__global__ __launch_bounds__(256) void scores_mfma(
    const f16* __restrict__ QK, float* __restrict__ S, int side)
{
    const int b = blockIdx.z;
    const f16* A = QK + ((size_t)(side * 2 + 0) * NB + b) * NP * CHID;  // Q [q][o]
    const f16* B = QK + ((size_t)(side * 2 + 1) * NB + b) * NP * CHID;  // K [p][o]
    float* Sb = S + (size_t)b * NP * NP;

    const int m0 = blockIdx.y * 128;   // q
    const int n0 = blockIdx.x * 128;   // p

    __shared__ __align__(16) f16 As[128 * 64];
    __shared__ __align__(16) f16 Bs[128 * 64];

    const int t = threadIdx.x, lane = t & 63, w = t >> 6;
    const int wm = w >> 1, wn = w & 1;

    f32x4 acc[4][4];
#pragma unroll
    for (int i = 0; i < 4; ++i)
#pragma unroll
        for (int j = 0; j < 4; ++j) acc[i][j] = (f32x4){0.f, 0.f, 0.f, 0.f};

    for (int k0 = 0; k0 < CHID; k0 += 64) {
        stage_f16(A, CHID, m0, k0, As, t);
        stage_f16(B, CHID, n0, k0, Bs, t);
        __syncthreads();
#pragma unroll
        for (int kh = 0; kh < 2; ++kh) {
            f16x8 a[4], bb[4];
#pragma unroll
            for (int fm = 0; fm < 4; ++fm)
                a[fm] = ldsfrag(As, wm * 64 + fm * 16 + (lane & 15),
                                kh * 64 + (lane >> 4) * 16);
#pragma unroll
            for (int fn = 0; fn < 4; ++fn)
                bb[fn] = ldsfrag(Bs, wn * 64 + fn * 16 + (lane & 15),
                                 kh * 64 + (lane >> 4) * 16);
#pragma unroll
            for (int fm = 0; fm < 4; ++fm)
#pragma unroll
                for (int fn = 0; fn < 4; ++fn)
                    acc[fm][fn] = __builtin_amdgcn_mfma_f32_16x16x32_f16(
                        a[fm], bb[fn], acc[fm][fn], 0, 0, 0);
        }
        __syncthreads();
    }

    const int lo4 = (lane >> 4) * 4, lp = lane & 15;
#pragma unroll
    for (int fm = 0; fm < 4; ++fm) {
#pragma unroll
        for (int fn = 0; fn < 4; ++fn) {
            const int q = m0 + wm * 64 + fm * 16 + lo4;
            const int p = n0 + wn * 64 + fn * 16 + lp;
#pragma unroll
            for (int r = 0; r < 4; ++r)
                Sb[(size_t)(q + r) * NP + p] = acc[fm][fn][r];
        }
    }
}

// ---------------------------------------------------------------------------
// Row softmax: one block per q-row. Reads S fp32 [q][p], writes attn f16 [q][p].
// ---------------------------------------------------------------------------
__global__ __launch_bounds__(256) void softmax_rows(
    const float* __restrict__ S, f16* __restrict__ attn)
{
    const size_t row = blockIdx.x;
    const float* Sr = S + row * NP;
    f16* Ar = attn + row * NP;
    const int t = threadIdx.x;

    const float4 v = *reinterpret_cast<const float4*>(&Sr[t * 4]);
    float m = fmaxf(fmaxf(v.x, v.y), fmaxf(v.z, v.w));
#pragma unroll
    for (int off = 32; off; off >>= 1) m = fmaxf(m, __shfl_xor(m, off));
    __shared__ float redm[4], reds[4];
    if ((t & 63) == 0) redm[t >> 6] = m;
    __syncthreads();
    m = fmaxf(fmaxf(redm[0], redm[1]), fmaxf(redm[2], redm[3]));

    float4 e;
    e.x = __expf(v.x - m); e.y = __expf(v.y - m);
    e.z = __expf(v.z - m); e.w = __expf(v.w - m);
    float s = e.x + e.y + e.z + e.w;
#pragma unroll
    for (int off = 32; off; off >>= 1) s += __shfl_xor(s, off);
    if ((t & 63) == 0) reds[t >> 6] = s;
    __syncthreads();
    const float inv = 1.0f / (reds[0] + reds[1] + reds[2] + reds[3]);

    union { f16 h[4]; uint2 u; } o;
    o.h[0] = (f16)(e.x * inv); o.h[1] = (f16)(e.y * inv);
    o.h[2] = (f16)(e.z * inv); o.h[3] = (f16)(e.w * inv);
    *reinterpret_cast<uint2*>(&Ar[t * 4]) = o.u;
}

// ---------------------------------------------------------------------------
// attended: out[c][q] = sum_p V[c][p]*attn[q][p]   (V fp32, converted f16 in-staging)
// ---------------------------------------------------------------------------
__global__ __launch_bounds__(256) void attended_mfma(
    const float* __restrict__ V, const f16* __restrict__ attn,
    float* __restrict__ out)
{
    const int b = blockIdx.z;
    const float* Vb = V + (size_t)b * CIN * NP;       // [c][p]
    const f16* Ab = attn + (size_t)b * NP * NP;       // [q][p]
    float* Ob = out + (size_t)b * CIN * NP;

    const int m0 = blockIdx.y * 128;   // c
    const int n0 = blockIdx.x * 128;   // q

    __shared__ __align__(16) f16 As[128 * 64];
    __shared__ __align__(16) f16 Bs[128 * 64];

    const int t = threadIdx.x, lane = t & 63, w = t >> 6;
    const int wm = w >> 1, wn = w & 1;

    f32x4 acc[4][4];
#pragma unroll
    for (int i = 0; i < 4; ++i)
#pragma unroll
        for (int j = 0; j < 4; ++j) acc[i][j] = (f32x4){0.f, 0.f, 0.f, 0.f};

    const int r0 = t >> 3, sl = t & 7;

    for (int k0 = 0; k0 < NP; k0 += 64) {
        // A tile: V fp32 -> f16 convert in staging
#pragma unroll
        for (int it = 0; it < 4; ++it) {
            const int row = r0 + it * 32;
            const float* src = &Vb[(size_t)(m0 + row) * NP + k0 + sl * 8];
            const float4 v0 = *reinterpret_cast<const float4*>(src);
            const float4 v1 = *reinterpret_cast<const float4*>(src + 4);
            union { f16 h[8]; int4 i4; } pk;
            pk.h[0] = (f16)v0.x; pk.h[1] = (f16)v0.y;
            pk.h[2] = (f16)v0.z; pk.h[3] = (f16)v0.w;
            pk.h[4] = (f16)v1.x; pk.h[5] = (f16)v1.y;
            pk.h[6] = (f16)v1.z; pk.h[7] = (f16)v1.w;
            const int byte = (row * 128 + sl * 16) ^ ((row & 7) << 4);
            *reinterpret_cast<int4*>(reinterpret_cast<char*>(As) + byte) = pk.i4;
        }
        stage_f16(Ab, NP, n0, k0, Bs, t);
        __syncthreads();
#pragma unroll
        for (int kh = 0; kh < 2; ++kh) {
            f16x8 a[4], bb[4];
#pragma unroll
            for (int fm = 0; fm < 4; ++fm)
                a[fm] = ldsfrag(As, wm * 64 + fm * 16 + (lane & 15),
                                kh * 64 + (lane >> 4) * 16);
#pragma unroll
            for (int fn = 0; fn < 4; ++fn)
                bb[fn] = ldsfrag(Bs, wn * 64 + fn * 16 + (lane & 15),
                                 kh * 64 + (lane >> 4) * 16);
#pragma unroll
            for (int fm = 0; fm < 4; ++fm)
#pragma unroll
                for (int fn = 0; fn < 4; ++fn)
                    acc[fm][fn] = __builtin_amdgcn_mfma_f32_16x16x32_f16(
                        a[fm], bb[fn], acc[fm][fn], 0, 0, 0);
        }
        __syncthreads();
    }

    const int lo4 = (lane >> 4) * 4, lp = lane & 15;
#pragma unroll
    for (int fm = 0; fm < 4; ++fm) {
#pragma unroll
        for (int fn = 0; fn < 4; ++fn) {
            const int c = m0 + wm * 64 + fm * 16 + lo4;
            const int q = n0 + wn * 64 + fn * 16 + lp;
#pragma unroll
            for (int r = 0; r < 4; ++r)
                Ob[(size_t)(c + r) * NP + q] = acc[fm][fn][r];
        }
    }
}

// ---------------------------------------------------------------------------
extern "C" void kernel_launch(void* const* d_in, const int* in_sizes, int n_in,
                              void* d_out, int out_size, void* d_ws, size_t ws_size,
                              hipStream_t stream)
{
    const float* f1  = (const float*)d_in[0];
    const float* f2  = (const float*)d_in[1];
    const float* Wq1 = (const float*)d_in[2];
    const float* bq1 = (const float*)d_in[3];
    const float* Wk1 = (const float*)d_in[4];
    const float* bk1 = (const float*)d_in[5];
    const float* Wq2 = (const float*)d_in[6];
    const float* bq2 = (const float*)d_in[7];
    const float* Wk2 = (const float*)d_in[8];
    const float* bk2 = (const float*)d_in[9];
    float* out = (float*)d_out;

    char* ws = (char*)d_ws;
    f16*   Ft   = (f16*)ws;                          // 67,108,864 B
    float* S    = (float*)ws;                        // reuse after proj
    f16*   attn = (f16*)(ws + 33554432);             // reuse
    f16*   QK   = (f16*)(ws + 67108864);             // 16,777,216 B
    f16*   Wf   = (f16*)(ws + 83886080);             //  4,194,304 B

    const dim3 blk(256);

    convert_W<<<dim3(4 * CHID * CIN / 4 / 256), blk, 0, stream>>>(
        Wq1, Wk1, Wq2, Wk2, Wf);
    convert_F<<<dim3(NP / 64, CIN / 64, 2 * NB), blk, 0, stream>>>(f1, f2, Ft);

    proj_mfma<<<dim3(NP / 128, CHID / 128, 4 * NB), blk, 0, stream>>>(
        Wf, Ft, bq1, bk1, bq2, bk2, QK);

    for (int side = 0; side < 2; ++side) {
        scores_mfma<<<dim3(NP / 128, NP / 128, NB), blk, 0, stream>>>(QK, S, side);
        softmax_rows<<<dim3(NB * NP), blk, 0, stream>>>(S, attn);
        const float* V = (side == 0) ? f2 : f1;
        float* o = out + (size_t)side * NB * CIN * NP;
        attended_mfma<<<dim3(NP / 128, CIN / 128, NB), blk, 0, stream>>>(V, attn, o);
    }
}

// Round 4
// 462.867 us; speedup vs baseline: 3.5486x; 1.1024x over previous
//
#include <hip/hip_runtime.h>
#include <math.h>

#define NB   8
#define CIN  2048
#define CHID 256
#define NP   1024

typedef _Float16 f16;
typedef _Float16 f16x8 __attribute__((ext_vector_type(8)));
typedef float    f32x4 __attribute__((ext_vector_type(4)));

// ---------------------------------------------------------------------------
// ws layout (bytes):
//   [0, 67108864)           : Ft f16 [2][NB][NP][CIN]   (convert+proj phase)
//       reused after proj:    S  f32 [NB][NP][NP] at 0        (33,554,432)
//                             attn f16 [NB][NP][NP] at 33554432 (16,777,216)
//   [67108864, 83886080)    : QK f16 [4][NB][NP][CHID]  (Q1,K1,Q2,K2, [p][o])
//   [83886080, 88080384)    : Wf16 [4][CHID][CIN]
// peak ws = 88,080,384 B
//
// XCD mapping (T1): hardware dispatches round-robin blockIdx over the 8 XCDs.
// NB==8, so batch = bid%8 pins each batch's working set to one XCD's L2.
// ---------------------------------------------------------------------------

// Stage a [128 outer][64 k] f16 tile into LDS with XOR-swizzled 16B slots.
__device__ inline void stage_f16(const f16* __restrict__ g, int stride,
                                 int outer0, int k0, f16* lds, int t)
{
    const int r0 = t >> 3;          // 0..31
    const int sl = t & 7;           // 16B slot within 128B row
#pragma unroll
    for (int it = 0; it < 4; ++it) {
        const int row = r0 + it * 32;
        const int4 v = *reinterpret_cast<const int4*>(
            &g[(size_t)(outer0 + row) * stride + k0 + sl * 8]);
        const int byte = (row * 128 + sl * 16) ^ ((row & 7) << 4);
        *reinterpret_cast<int4*>(reinterpret_cast<char*>(lds) + byte) = v;
    }
}

// Read one MFMA fragment (8 contiguous k at one row) from swizzled LDS tile.
__device__ inline f16x8 ldsfrag(const f16* lds, int row, int kbyte)
{
    const char* p = reinterpret_cast<const char*>(lds) +
                    ((row * 128 + kbyte) ^ ((row & 7) << 4));
    return *reinterpret_cast<const f16x8*>(p);
}

// ---------------------------------------------------------------------------
// convert_W: 4 weight mats fp32 [CHID][CIN] -> f16, same layout
// ---------------------------------------------------------------------------
__global__ __launch_bounds__(256) void convert_W(
    const float* __restrict__ Wq1, const float* __restrict__ Wk1,
    const float* __restrict__ Wq2, const float* __restrict__ Wk2,
    f16* __restrict__ Wf)
{
    const int n4 = CHID * CIN / 4;               // float4 chunks per mat
    const int i = blockIdx.x * 256 + threadIdx.x; // 0 .. 4*n4-1
    const int mat = i / n4;
    const int j = i - mat * n4;
    const float* W = (mat == 0) ? Wq1 : (mat == 1) ? Wk1 : (mat == 2) ? Wq2 : Wk2;
    const float4 v = *reinterpret_cast<const float4*>(&W[(size_t)j * 4]);
    union { f16 h[4]; uint2 u; } o;
    o.h[0] = (f16)v.x; o.h[1] = (f16)v.y; o.h[2] = (f16)v.z; o.h[3] = (f16)v.w;
    *reinterpret_cast<uint2*>(&Wf[(size_t)i * 4]) = o.u;
}

// ---------------------------------------------------------------------------
// convert_F: F fp32 [b][c][p] -> Ft f16 [feat][b][p][c] (transposed per batch)
// 64x64 tiles through LDS.
// ---------------------------------------------------------------------------
__global__ __launch_bounds__(256) void convert_F(
    const float* __restrict__ f1, const float* __restrict__ f2,
    f16* __restrict__ Ft)
{
    const int z = blockIdx.z;               // feat*NB + b
    const int feat = z >> 3, b = z & 7;
    const float* F = (feat ? f2 : f1) + (size_t)b * CIN * NP;
    f16* T = Ft + ((size_t)feat * NB + b) * NP * CIN;
    const int c0 = blockIdx.y * 64, p0 = blockIdx.x * 64;

    __shared__ float tile[64][65];
    const int t = threadIdx.x;
    const int r = t >> 4, c4 = (t & 15) * 4;

#pragma unroll
    for (int it = 0; it < 4; ++it) {
        const int cr = r + it * 16;
        const float4 v = *reinterpret_cast<const float4*>(
            &F[(size_t)(c0 + cr) * NP + p0 + c4]);
        tile[cr][c4 + 0] = v.x;
        tile[cr][c4 + 1] = v.y;
        tile[cr][c4 + 2] = v.z;
        tile[cr][c4 + 3] = v.w;
    }
    __syncthreads();
#pragma unroll
    for (int it = 0; it < 4; ++it) {
        const int pr = r + it * 16;
        union { f16 h[4]; uint2 u; } o;
        o.h[0] = (f16)tile[c4 + 0][pr];
        o.h[1] = (f16)tile[c4 + 1][pr];
        o.h[2] = (f16)tile[c4 + 2][pr];
        o.h[3] = (f16)tile[c4 + 3][pr];
        *reinterpret_cast<uint2*>(&T[(size_t)(p0 + pr) * CIN + c0 + c4]) = o.u;
    }
}

// ---------------------------------------------------------------------------
// proj: QK[mat][b][p][o] = f16( sum_c W[o][c]*F[c][p] + bias[o] )
// A = Wf16 [o][c], B = Ft [p][c]. 128x128 tile, K-step 64, 4 waves 2x2.
// Grid: 512 blocks 1D. batch = bid%8 (-> XCD); per XCD the 64 blocks run
// mats {0,3} (Ft[f1][b] slab) then {1,2} (Ft[f2][b] slab), tiles fastest.
// ---------------------------------------------------------------------------
__global__ __launch_bounds__(256) void proj_mfma(
    const f16* __restrict__ Wf, const f16* __restrict__ Ft,
    const float* __restrict__ bq1, const float* __restrict__ bk1,
    const float* __restrict__ bq2, const float* __restrict__ bk2,
    f16* __restrict__ QK)
{
    const int bid = blockIdx.x;
    const int b = bid & 7;
    const int within = bid >> 3;            // 0..63
    const int tile = within & 15;           // 16 tiles
    const int mat_in_pair = (within >> 4) & 1;
    const int pairsel = within >> 5;        // 0: mats {0,3}, 1: mats {1,2}
    const int mat = pairsel == 0 ? (mat_in_pair ? 3 : 0)
                                 : (mat_in_pair ? 2 : 1);

    const f16* A = Wf + (size_t)mat * CHID * CIN;
    const int feat = (mat == 0 || mat == 3) ? 0 : 1;  // Q1:f1 K1:f2 Q2:f2 K2:f1
    const f16* B = Ft + ((size_t)feat * NB + b) * NP * CIN;
    const float* bias = (mat == 0) ? bq1 : (mat == 1) ? bk1 : (mat == 2) ? bq2 : bk2;
    f16* C = QK + ((size_t)mat * NB + b) * NP * CHID;   // [p][o]

    const int m0 = (tile >> 3) * 128;   // o (2 tiles)
    const int n0 = (tile & 7) * 128;    // p (8 tiles)

    __shared__ __align__(16) f16 As[128 * 64];
    __shared__ __align__(16) f16 Bs[128 * 64];

    const int t = threadIdx.x, lane = t & 63, w = t >> 6;
    const int wm = w >> 1, wn = w & 1;

    f32x4 acc[4][4];
#pragma unroll
    for (int i = 0; i < 4; ++i)
#pragma unroll
        for (int j = 0; j < 4; ++j) acc[i][j] = (f32x4){0.f, 0.f, 0.f, 0.f};

    for (int k0 = 0; k0 < CIN; k0 += 64) {
        stage_f16(A, CIN, m0, k0, As, t);
        stage_f16(B, CIN, n0, k0, Bs, t);
        __syncthreads();
#pragma unroll
        for (int kh = 0; kh < 2; ++kh) {
            f16x8 a[4], bb[4];
#pragma unroll
            for (int fm = 0; fm < 4; ++fm)
                a[fm] = ldsfrag(As, wm * 64 + fm * 16 + (lane & 15),
                                kh * 64 + (lane >> 4) * 16);
#pragma unroll
            for (int fn = 0; fn < 4; ++fn)
                bb[fn] = ldsfrag(Bs, wn * 64 + fn * 16 + (lane & 15),
                                 kh * 64 + (lane >> 4) * 16);
#pragma unroll
            for (int fm = 0; fm < 4; ++fm)
#pragma unroll
                for (int fn = 0; fn < 4; ++fn)
                    acc[fm][fn] = __builtin_amdgcn_mfma_f32_16x16x32_f16(
                        a[fm], bb[fn], acc[fm][fn], 0, 0, 0);
        }
        __syncthreads();
    }

    const int lo4 = (lane >> 4) * 4, lp = lane & 15;
#pragma unroll
    for (int fm = 0; fm < 4; ++fm) {
        const int obase = m0 + wm * 64 + fm * 16 + lo4;
        const float4 b4 = *reinterpret_cast<const float4*>(&bias[obase]);
#pragma unroll
        for (int fn = 0; fn < 4; ++fn) {
            const int p = n0 + wn * 64 + fn * 16 + lp;
            union { f16 h[4]; uint2 u; } o;
            o.h[0] = (f16)(acc[fm][fn][0] + b4.x);
            o.h[1] = (f16)(acc[fm][fn][1] + b4.y);
            o.h[2] = (f16)(acc[fm][fn][2] + b4.z);
            o.h[3] = (f16)(acc[fm][fn][3] + b4.w);
            *reinterpret_cast<uint2*>(&C[(size_t)p * CHID + obase]) = o.u;
        }
    }
}

// ---------------------------------------------------------------------------
// scores: S[q][p] = sum_o Q[q][o]*K[p][o]   (fp32 logits)
// Grid: 512 blocks 1D. batch = bid%8; Q(b)+K(b) slabs (1 MB) stay L2-resident.
// ---------------------------------------------------------------------------
__global__ __launch_bounds__(256) void scores_mfma(
    const f16* __restrict__ QK, float* __restrict__ S, int side)
{
    const int bid = blockIdx.x;
    const int b = bid & 7;
    const int tile = bid >> 3;              // 0..63
    const f16* A = QK + ((size_t)(side * 2 + 0) * NB + b) * NP * CHID;  // Q [q][o]
    const f16* B = QK + ((size_t)(side * 2 + 1) * NB + b) * NP * CHID;  // K [p][o]
    float* Sb = S + (size_t)b * NP * NP;

    const int m0 = (tile >> 3) * 128;   // q
    const int n0 = (tile & 7) * 128;    // p

    __shared__ __align__(16) f16 As[128 * 64];
    __shared__ __align__(16) f16 Bs[128 * 64];

    const int t = threadIdx.x, lane = t & 63, w = t >> 6;
    const int wm = w >> 1, wn = w & 1;

    f32x4 acc[4][4];
#pragma unroll
    for (int i = 0; i < 4; ++i)
#pragma unroll
        for (int j = 0; j < 4; ++j) acc[i][j] = (f32x4){0.f, 0.f, 0.f, 0.f};

    for (int k0 = 0; k0 < CHID; k0 += 64) {
        stage_f16(A, CHID, m0, k0, As, t);
        stage_f16(B, CHID, n0, k0, Bs, t);
        __syncthreads();
#pragma unroll
        for (int kh = 0; kh < 2; ++kh) {
            f16x8 a[4], bb[4];
#pragma unroll
            for (int fm = 0; fm < 4; ++fm)
                a[fm] = ldsfrag(As, wm * 64 + fm * 16 + (lane & 15),
                                kh * 64 + (lane >> 4) * 16);
#pragma unroll
            for (int fn = 0; fn < 4; ++fn)
                bb[fn] = ldsfrag(Bs, wn * 64 + fn * 16 + (lane & 15),
                                 kh * 64 + (lane >> 4) * 16);
#pragma unroll
            for (int fm = 0; fm < 4; ++fm)
#pragma unroll
                for (int fn = 0; fn < 4; ++fn)
                    acc[fm][fn] = __builtin_amdgcn_mfma_f32_16x16x32_f16(
                        a[fm], bb[fn], acc[fm][fn], 0, 0, 0);
        }
        __syncthreads();
    }

    const int lo4 = (lane >> 4) * 4, lp = lane & 15;
#pragma unroll
    for (int fm = 0; fm < 4; ++fm) {
#pragma unroll
        for (int fn = 0; fn < 4; ++fn) {
            const int q = m0 + wm * 64 + fm * 16 + lo4;
            const int p = n0 + wn * 64 + fn * 16 + lp;
#pragma unroll
            for (int r = 0; r < 4; ++r)
                Sb[(size_t)(q + r) * NP + p] = acc[fm][fn][r];
        }
    }
}

// ---------------------------------------------------------------------------
// Row softmax: one block per q-row. Reads S fp32 [q][p], writes attn f16 [q][p].
// ---------------------------------------------------------------------------
__global__ __launch_bounds__(256) void softmax_rows(
    const float* __restrict__ S, f16* __restrict__ attn)
{
    const size_t row = blockIdx.x;
    const float* Sr = S + row * NP;
    f16* Ar = attn + row * NP;
    const int t = threadIdx.x;

    const float4 v = *reinterpret_cast<const float4*>(&Sr[t * 4]);
    float m = fmaxf(fmaxf(v.x, v.y), fmaxf(v.z, v.w));
#pragma unroll
    for (int off = 32; off; off >>= 1) m = fmaxf(m, __shfl_xor(m, off));
    __shared__ float redm[4], reds[4];
    if ((t & 63) == 0) redm[t >> 6] = m;
    __syncthreads();
    m = fmaxf(fmaxf(redm[0], redm[1]), fmaxf(redm[2], redm[3]));

    float4 e;
    e.x = __expf(v.x - m); e.y = __expf(v.y - m);
    e.z = __expf(v.z - m); e.w = __expf(v.w - m);
    float s = e.x + e.y + e.z + e.w;
#pragma unroll
    for (int off = 32; off; off >>= 1) s += __shfl_xor(s, off);
    if ((t & 63) == 0) reds[t >> 6] = s;
    __syncthreads();
    const float inv = 1.0f / (reds[0] + reds[1] + reds[2] + reds[3]);

    union { f16 h[4]; uint2 u; } o;
    o.h[0] = (f16)(e.x * inv); o.h[1] = (f16)(e.y * inv);
    o.h[2] = (f16)(e.z * inv); o.h[3] = (f16)(e.w * inv);
    *reinterpret_cast<uint2*>(&Ar[t * 4]) = o.u;
}

// ---------------------------------------------------------------------------
// attended: out[c][q] = sum_p V[c][p]*attn[q][p]   (V fp32, converted f16 in-staging)
// Grid: 1024 blocks 1D. batch = bid%8 (-> XCD). Within a batch, q-tiles run
// fastest so the 8 blocks sharing a V c-tile are consecutive/co-resident;
// the batch's whole attn (2 MB) stays L2-resident.
// ---------------------------------------------------------------------------
__global__ __launch_bounds__(256) void attended_mfma(
    const float* __restrict__ V, const f16* __restrict__ attn,
    float* __restrict__ out)
{
    const int bid = blockIdx.x;
    const int b = bid & 7;
    const int tile = bid >> 3;              // 0..127
    const int qt = tile & 7;                // q fastest
    const int ct = tile >> 3;               // 0..15

    const float* Vb = V + (size_t)b * CIN * NP;       // [c][p]
    const f16* Ab = attn + (size_t)b * NP * NP;       // [q][p]
    float* Ob = out + (size_t)b * CIN * NP;

    const int m0 = ct * 128;   // c
    const int n0 = qt * 128;   // q

    __shared__ __align__(16) f16 As[128 * 64];
    __shared__ __align__(16) f16 Bs[128 * 64];

    const int t = threadIdx.x, lane = t & 63, w = t >> 6;
    const int wm = w >> 1, wn = w & 1;

    f32x4 acc[4][4];
#pragma unroll
    for (int i = 0; i < 4; ++i)
#pragma unroll
        for (int j = 0; j < 4; ++j) acc[i][j] = (f32x4){0.f, 0.f, 0.f, 0.f};

    const int r0 = t >> 3, sl = t & 7;

    for (int k0 = 0; k0 < NP; k0 += 64) {
        // A tile: V fp32 -> f16 convert in staging
#pragma unroll
        for (int it = 0; it < 4; ++it) {
            const int row = r0 + it * 32;
            const float* src = &Vb[(size_t)(m0 + row) * NP + k0 + sl * 8];
            const float4 v0 = *reinterpret_cast<const float4*>(src);
            const float4 v1 = *reinterpret_cast<const float4*>(src + 4);
            union { f16 h[8]; int4 i4; } pk;
            pk.h[0] = (f16)v0.x; pk.h[1] = (f16)v0.y;
            pk.h[2] = (f16)v0.z; pk.h[3] = (f16)v0.w;
            pk.h[4] = (f16)v1.x; pk.h[5] = (f16)v1.y;
            pk.h[6] = (f16)v1.z; pk.h[7] = (f16)v1.w;
            const int byte = (row * 128 + sl * 16) ^ ((row & 7) << 4);
            *reinterpret_cast<int4*>(reinterpret_cast<char*>(As) + byte) = pk.i4;
        }
        stage_f16(Ab, NP, n0, k0, Bs, t);
        __syncthreads();
#pragma unroll
        for (int kh = 0; kh < 2; ++kh) {
            f16x8 a[4], bb[4];
#pragma unroll
            for (int fm = 0; fm < 4; ++fm)
                a[fm] = ldsfrag(As, wm * 64 + fm * 16 + (lane & 15),
                                kh * 64 + (lane >> 4) * 16);
#pragma unroll
            for (int fn = 0; fn < 4; ++fn)
                bb[fn] = ldsfrag(Bs, wn * 64 + fn * 16 + (lane & 15),
                                 kh * 64 + (lane >> 4) * 16);
#pragma unroll
            for (int fm = 0; fm < 4; ++fm)
#pragma unroll
                for (int fn = 0; fn < 4; ++fn)
                    acc[fm][fn] = __builtin_amdgcn_mfma_f32_16x16x32_f16(
                        a[fm], bb[fn], acc[fm][fn], 0, 0, 0);
        }
        __syncthreads();
    }

    const int lo4 = (lane >> 4) * 4, lp = lane & 15;
#pragma unroll
    for (int fm = 0; fm < 4; ++fm) {
#pragma unroll
        for (int fn = 0; fn < 4; ++fn) {
            const int c = m0 + wm * 64 + fm * 16 + lo4;
            const int q = n0 + wn * 64 + fn * 16 + lp;
#pragma unroll
            for (int r = 0; r < 4; ++r)
                Ob[(size_t)(c + r) * NP + q] = acc[fm][fn][r];
        }
    }
}

// ---------------------------------------------------------------------------
extern "C" void kernel_launch(void* const* d_in, const int* in_sizes, int n_in,
                              void* d_out, int out_size, void* d_ws, size_t ws_size,
                              hipStream_t stream)
{
    const float* f1  = (const float*)d_in[0];
    const float* f2  = (const float*)d_in[1];
    const float* Wq1 = (const float*)d_in[2];
    const float* bq1 = (const float*)d_in[3];
    const float* Wk1 = (const float*)d_in[4];
    const float* bk1 = (const float*)d_in[5];
    const float* Wq2 = (const float*)d_in[6];
    const float* bq2 = (const float*)d_in[7];
    const float* Wk2 = (const float*)d_in[8];
    const float* bk2 = (const float*)d_in[9];
    float* out = (float*)d_out;

    char* ws = (char*)d_ws;
    f16*   Ft   = (f16*)ws;                          // 67,108,864 B
    float* S    = (float*)ws;                        // reuse after proj
    f16*   attn = (f16*)(ws + 33554432);             // reuse
    f16*   QK   = (f16*)(ws + 67108864);             // 16,777,216 B
    f16*   Wf   = (f16*)(ws + 83886080);             //  4,194,304 B

    const dim3 blk(256);

    convert_W<<<dim3(4 * CHID * CIN / 4 / 256), blk, 0, stream>>>(
        Wq1, Wk1, Wq2, Wk2, Wf);
    convert_F<<<dim3(NP / 64, CIN / 64, 2 * NB), blk, 0, stream>>>(f1, f2, Ft);

    proj_mfma<<<dim3(512), blk, 0, stream>>>(
        Wf, Ft, bq1, bk1, bq2, bk2, QK);

    for (int side = 0; side < 2; ++side) {
        scores_mfma<<<dim3(512), blk, 0, stream>>>(QK, S, side);
        softmax_rows<<<dim3(NB * NP), blk, 0, stream>>>(S, attn);
        const float* V = (side == 0) ? f2 : f1;
        float* o = out + (size_t)side * NB * CIN * NP;
        attended_mfma<<<dim3(1024), blk, 0, stream>>>(V, attn, o);
    }
}

// Round 6
// 441.183 us; speedup vs baseline: 3.7230x; 1.0492x over previous
//
#include <hip/hip_runtime.h>
#include <math.h>

#define NB   8
#define CIN  2048
#define CHID 256
#define NP   1024

typedef _Float16 f16;
typedef _Float16 f16x8 __attribute__((ext_vector_type(8)));
typedef float    f32x4 __attribute__((ext_vector_type(4)));

typedef const __attribute__((address_space(1))) void GAS;
typedef __attribute__((address_space(3))) void LAS;

// ---------------------------------------------------------------------------
// ws layout (bytes):
//   [0, 67108864)           : Ft f16 [2][NB][NP][CIN]   (proj phase)
//       reused after proj:    S  f32 [NB][NP][NP] at 0         (33,554,432)
//                             attn f16 [NB][NP][NP] at 33554432 (16,777,216)
//   [67108864,  83886080)   : QK f16 [4][NB][NP][CHID]  (Q1,K1,Q2,K2, [p][o])
//   [83886080,  88080384)   : Wf16 [4][CHID][CIN]
//   [88080384, 155189248)   : Vf f16 [2][NB][CIN][NP]   (attended A operand)
// peak ws = 155,189,248 B  (poison fill shows ws_size = 512 MiB)
//
// XCD mapping (T1, verified R4: attended FETCH 270->49 MB): batch = bid%8.
// ---------------------------------------------------------------------------

// Stage a [128 outer][64 k] f16 tile into LDS via global_load_lds dwordx4.
// LDS is written LINEARLY (HW: wave-uniform base + lane*16); the swizzle is
// applied on the GLOBAL source slot: lane l of chunk c reads slot (l&7)^(l>>3)
// of row c*8+(l>>3). Read side applies the same XOR -> net identity (rule 21).
__device__ inline void stage_gl(const f16* __restrict__ g, int stride,
                                int outer0, int k0, f16* lds, int t)
{
    const int lane = t & 63, w = t >> 6;
    const int r8 = lane >> 3;             // 0..7  (row within chunk)
    const int xsl = (lane & 7) ^ r8;      // pre-swizzled 16B slot
#pragma unroll
    for (int it = 0; it < 4; ++it) {
        const int chunk = w * 4 + it;     // 0..15
        const int row = chunk * 8 + r8;   // 0..127
        const f16* src = &g[(size_t)(outer0 + row) * stride + k0 + xsl * 8];
        __builtin_amdgcn_global_load_lds(
            (GAS*)src, (LAS*)(reinterpret_cast<char*>(lds) + chunk * 1024),
            16, 0, 0);
    }
}

// Read one MFMA fragment (8 contiguous k at one row) from swizzled LDS tile.
__device__ inline f16x8 ldsfrag(const f16* lds, int row, int kbyte)
{
    const char* p = reinterpret_cast<const char*>(lds) +
                    ((row * 128 + kbyte) ^ ((row & 7) << 4));
    return *reinterpret_cast<const f16x8*>(p);
}

// ---------------------------------------------------------------------------
// convert_W: 4 weight mats fp32 [CHID][CIN] -> f16, same layout
// ---------------------------------------------------------------------------
__global__ __launch_bounds__(256) void convert_W(
    const float* __restrict__ Wq1, const float* __restrict__ Wk1,
    const float* __restrict__ Wq2, const float* __restrict__ Wk2,
    f16* __restrict__ Wf)
{
    const int n4 = CHID * CIN / 4;
    const int i = blockIdx.x * 256 + threadIdx.x;
    const int mat = i / n4;
    const int j = i - mat * n4;
    const float* W = (mat == 0) ? Wq1 : (mat == 1) ? Wk1 : (mat == 2) ? Wq2 : Wk2;
    const float4 v = *reinterpret_cast<const float4*>(&W[(size_t)j * 4]);
    union { f16 h[4]; uint2 u; } o;
    o.h[0] = (f16)v.x; o.h[1] = (f16)v.y; o.h[2] = (f16)v.z; o.h[3] = (f16)v.w;
    *reinterpret_cast<uint2*>(&Wf[(size_t)i * 4]) = o.u;
}

// ---------------------------------------------------------------------------
// convert_F: F fp32 [b][c][p] -> Ft f16 [feat][b][p][c] (transposed, for proj)
//                             -> Vf f16 [feat][b][c][p] (straight, for attended)
// 64x64 tiles through LDS.
// ---------------------------------------------------------------------------
__global__ __launch_bounds__(256) void convert_F(
    const float* __restrict__ f1, const float* __restrict__ f2,
    f16* __restrict__ Ft, f16* __restrict__ Vf)
{
    const int z = blockIdx.z;               // feat*NB + b
    const int feat = z >> 3, b = z & 7;
    const float* F = (feat ? f2 : f1) + (size_t)b * CIN * NP;
    f16* T = Ft + ((size_t)feat * NB + b) * NP * CIN;
    f16* Vb = Vf + ((size_t)feat * NB + b) * CIN * NP;
    const int c0 = blockIdx.y * 64, p0 = blockIdx.x * 64;

    __shared__ float tile[64][65];
    const int t = threadIdx.x;
    const int r = t >> 4, c4 = (t & 15) * 4;

#pragma unroll
    for (int it = 0; it < 4; ++it) {
        const int cr = r + it * 16;
        const float4 v = *reinterpret_cast<const float4*>(
            &F[(size_t)(c0 + cr) * NP + p0 + c4]);
        tile[cr][c4 + 0] = v.x;
        tile[cr][c4 + 1] = v.y;
        tile[cr][c4 + 2] = v.z;
        tile[cr][c4 + 3] = v.w;
        // straight f16 copy for attended (V operand)
        union { f16 h[4]; uint2 u; } s;
        s.h[0] = (f16)v.x; s.h[1] = (f16)v.y; s.h[2] = (f16)v.z; s.h[3] = (f16)v.w;
        *reinterpret_cast<uint2*>(&Vb[(size_t)(c0 + cr) * NP + p0 + c4]) = s.u;
    }
    __syncthreads();
#pragma unroll
    for (int it = 0; it < 4; ++it) {
        const int pr = r + it * 16;
        union { f16 h[4]; uint2 u; } o;
        o.h[0] = (f16)tile[c4 + 0][pr];
        o.h[1] = (f16)tile[c4 + 1][pr];
        o.h[2] = (f16)tile[c4 + 2][pr];
        o.h[3] = (f16)tile[c4 + 3][pr];
        *reinterpret_cast<uint2*>(&T[(size_t)(p0 + pr) * CIN + c0 + c4]) = o.u;
    }
}

// ---------------------------------------------------------------------------
// proj: QK[mat][b][p][o] = f16( sum_c W[o][c]*F[c][p] + bias[o] )
// A = Wf16 [o][c], B = Ft [p][c]. 128x128 tile, K-step 64, 4 waves 2x2.
// Grid 512 1D: batch = bid%8 (XCD); per XCD mats {0,3} then {1,2}.
// ---------------------------------------------------------------------------
__global__ __launch_bounds__(256) void proj_mfma(
    const f16* __restrict__ Wf, const f16* __restrict__ Ft,
    const float* __restrict__ bq1, const float* __restrict__ bk1,
    const float* __restrict__ bq2, const float* __restrict__ bk2,
    f16* __restrict__ QK)
{
    const int bid = blockIdx.x;
    const int b = bid & 7;
    const int within = bid >> 3;            // 0..63
    const int tile = within & 15;
    const int mat_in_pair = (within >> 4) & 1;
    const int pairsel = within >> 5;
    const int mat = pairsel == 0 ? (mat_in_pair ? 3 : 0)
                                 : (mat_in_pair ? 2 : 1);

    const f16* A = Wf + (size_t)mat * CHID * CIN;
    const int feat = (mat == 0 || mat == 3) ? 0 : 1;
    const f16* B = Ft + ((size_t)feat * NB + b) * NP * CIN;
    const float* bias = (mat == 0) ? bq1 : (mat == 1) ? bk1 : (mat == 2) ? bq2 : bk2;
    f16* C = QK + ((size_t)mat * NB + b) * NP * CHID;

    const int m0 = (tile >> 3) * 128;   // o
    const int n0 = (tile & 7) * 128;    // p

    __shared__ __align__(16) f16 As[128 * 64];
    __shared__ __align__(16) f16 Bs[128 * 64];

    const int t = threadIdx.x, lane = t & 63, w = t >> 6;
    const int wm = w >> 1, wn = w & 1;

    f32x4 acc[4][4];
#pragma unroll
    for (int i = 0; i < 4; ++i)
#pragma unroll
        for (int j = 0; j < 4; ++j) acc[i][j] = (f32x4){0.f, 0.f, 0.f, 0.f};

    for (int k0 = 0; k0 < CIN; k0 += 64) {
        stage_gl(A, CIN, m0, k0, As, t);
        stage_gl(B, CIN, n0, k0, Bs, t);
        __syncthreads();
#pragma unroll
        for (int kh = 0; kh < 2; ++kh) {
            f16x8 a[4], bb[4];
#pragma unroll
            for (int fm = 0; fm < 4; ++fm)
                a[fm] = ldsfrag(As, wm * 64 + fm * 16 + (lane & 15),
                                kh * 64 + (lane >> 4) * 16);
#pragma unroll
            for (int fn = 0; fn < 4; ++fn)
                bb[fn] = ldsfrag(Bs, wn * 64 + fn * 16 + (lane & 15),
                                 kh * 64 + (lane >> 4) * 16);
#pragma unroll
            for (int fm = 0; fm < 4; ++fm)
#pragma unroll
                for (int fn = 0; fn < 4; ++fn)
                    acc[fm][fn] = __builtin_amdgcn_mfma_f32_16x16x32_f16(
                        a[fm], bb[fn], acc[fm][fn], 0, 0, 0);
        }
        __syncthreads();
    }

    const int lo4 = (lane >> 4) * 4, lp = lane & 15;
#pragma unroll
    for (int fm = 0; fm < 4; ++fm) {
        const int obase = m0 + wm * 64 + fm * 16 + lo4;
        const float4 b4 = *reinterpret_cast<const float4*>(&bias[obase]);
#pragma unroll
        for (int fn = 0; fn < 4; ++fn) {
            const int p = n0 + wn * 64 + fn * 16 + lp;
            union { f16 h[4]; uint2 u; } o;
            o.h[0] = (f16)(acc[fm][fn][0] + b4.x);
            o.h[1] = (f16)(acc[fm][fn][1] + b4.y);
            o.h[2] = (f16)(acc[fm][fn][2] + b4.z);
            o.h[3] = (f16)(acc[fm][fn][3] + b4.w);
            *reinterpret_cast<uint2*>(&C[(size_t)p * CHID + obase]) = o.u;
        }
    }
}

// ---------------------------------------------------------------------------
// scores: S[q][p] = sum_o Q[q][o]*K[p][o]   (fp32 logits)
// Grid 512 1D: batch = bid%8; Q(b)+K(b) slabs (1 MB) L2-resident.
// ---------------------------------------------------------------------------
__global__ __launch_bounds__(256) void scores_mfma(
    const f16* __restrict__ QK, float* __restrict__ S, int side)
{
    const int bid = blockIdx.x;
    const int b = bid & 7;
    const int tile = bid >> 3;
    const f16* A = QK + ((size_t)(side * 2 + 0) * NB + b) * NP * CHID;
    const f16* B = QK + ((size_t)(side * 2 + 1) * NB + b) * NP * CHID;
    float* Sb = S + (size_t)b * NP * NP;

    const int m0 = (tile >> 3) * 128;   // q
    const int n0 = (tile & 7) * 128;    // p

    __shared__ __align__(16) f16 As[128 * 64];
    __shared__ __align__(16) f16 Bs[128 * 64];

    const int t = threadIdx.x, lane = t & 63, w = t >> 6;
    const int wm = w >> 1, wn = w & 1;

    f32x4 acc[4][4];
#pragma unroll
    for (int i = 0; i < 4; ++i)
#pragma unroll
        for (int j = 0; j < 4; ++j) acc[i][j] = (f32x4){0.f, 0.f, 0.f, 0.f};

    for (int k0 = 0; k0 < CHID; k0 += 64) {
        stage_gl(A, CHID, m0, k0, As, t);
        stage_gl(B, CHID, n0, k0, Bs, t);
        __syncthreads();
#pragma unroll
        for (int kh = 0; kh < 2; ++kh) {
            f16x8 a[4], bb[4];
#pragma unroll
            for (int fm = 0; fm < 4; ++fm)
                a[fm] = ldsfrag(As, wm * 64 + fm * 16 + (lane & 15),
                                kh * 64 + (lane >> 4) * 16);
#pragma unroll
            for (int fn = 0; fn < 4; ++fn)
                bb[fn] = ldsfrag(Bs, wn * 64 + fn * 16 + (lane & 15),
                                 kh * 64 + (lane >> 4) * 16);
#pragma unroll
            for (int fm = 0; fm < 4; ++fm)
#pragma unroll
                for (int fn = 0; fn < 4; ++fn)
                    acc[fm][fn] = __builtin_amdgcn_mfma_f32_16x16x32_f16(
                        a[fm], bb[fn], acc[fm][fn], 0, 0, 0);
        }
        __syncthreads();
    }

    const int lo4 = (lane >> 4) * 4, lp = lane & 15;
#pragma unroll
    for (int fm = 0; fm < 4; ++fm) {
#pragma unroll
        for (int fn = 0; fn < 4; ++fn) {
            const int q = m0 + wm * 64 + fm * 16 + lo4;
            const int p = n0 + wn * 64 + fn * 16 + lp;
#pragma unroll
            for (int r = 0; r < 4; ++r)
                Sb[(size_t)(q + r) * NP + p] = acc[fm][fn][r];
        }
    }
}

// ---------------------------------------------------------------------------
// Row softmax: one block per q-row. Reads S fp32 [q][p], writes attn f16 [q][p].
// ---------------------------------------------------------------------------
__global__ __launch_bounds__(256) void softmax_rows(
    const float* __restrict__ S, f16* __restrict__ attn)
{
    const size_t row = blockIdx.x;
    const float* Sr = S + row * NP;
    f16* Ar = attn + row * NP;
    const int t = threadIdx.x;

    const float4 v = *reinterpret_cast<const float4*>(&Sr[t * 4]);
    float m = fmaxf(fmaxf(v.x, v.y), fmaxf(v.z, v.w));
#pragma unroll
    for (int off = 32; off; off >>= 1) m = fmaxf(m, __shfl_xor(m, off));
    __shared__ float redm[4], reds[4];
    if ((t & 63) == 0) redm[t >> 6] = m;
    __syncthreads();
    m = fmaxf(fmaxf(redm[0], redm[1]), fmaxf(redm[2], redm[3]));

    float4 e;
    e.x = __expf(v.x - m); e.y = __expf(v.y - m);
    e.z = __expf(v.z - m); e.w = __expf(v.w - m);
    float s = e.x + e.y + e.z + e.w;
#pragma unroll
    for (int off = 32; off; off >>= 1) s += __shfl_xor(s, off);
    if ((t & 63) == 0) reds[t >> 6] = s;
    __syncthreads();
    const float inv = 1.0f / (reds[0] + reds[1] + reds[2] + reds[3]);

    union { f16 h[4]; uint2 u; } o;
    o.h[0] = (f16)(e.x * inv); o.h[1] = (f16)(e.y * inv);
    o.h[2] = (f16)(e.z * inv); o.h[3] = (f16)(e.w * inv);
    *reinterpret_cast<uint2*>(&Ar[t * 4]) = o.u;
}

// ---------------------------------------------------------------------------
// attended: out[c][q] = sum_p Vf[c][p]*attn[q][p]   (both f16, gload_lds)
// Grid 1024 1D: batch = bid%8 (XCD), q-tiles fastest (V c-tile reuse in L2).
// ---------------------------------------------------------------------------
__global__ __launch_bounds__(256) void attended_mfma(
    const f16* __restrict__ Vf, const f16* __restrict__ attn,
    float* __restrict__ out)
{
    const int bid = blockIdx.x;
    const int b = bid & 7;
    const int tile = bid >> 3;              // 0..127
    const int qt = tile & 7;                // q fastest
    const int ct = tile >> 3;               // 0..15

    const f16* Vb = Vf + (size_t)b * CIN * NP;        // [c][p]
    const f16* Ab = attn + (size_t)b * NP * NP;       // [q][p]
    float* Ob = out + (size_t)b * CIN * NP;

    const int m0 = ct * 128;   // c
    const int n0 = qt * 128;   // q

    __shared__ __align__(16) f16 As[128 * 64];
    __shared__ __align__(16) f16 Bs[128 * 64];

    const int t = threadIdx.x, lane = t & 63, w = t >> 6;
    const int wm = w >> 1, wn = w & 1;

    f32x4 acc[4][4];
#pragma unroll
    for (int i = 0; i < 4; ++i)
#pragma unroll
        for (int j = 0; j < 4; ++j) acc[i][j] = (f32x4){0.f, 0.f, 0.f, 0.f};

    for (int k0 = 0; k0 < NP; k0 += 64) {
        stage_gl(Vb, NP, m0, k0, As, t);
        stage_gl(Ab, NP, n0, k0, Bs, t);
        __syncthreads();
#pragma unroll
        for (int kh = 0; kh < 2; ++kh) {
            f16x8 a[4], bb[4];
#pragma unroll
            for (int fm = 0; fm < 4; ++fm)
                a[fm] = ldsfrag(As, wm * 64 + fm * 16 + (lane & 15),
                                kh * 64 + (lane >> 4) * 16);
#pragma unroll
            for (int fn = 0; fn < 4; ++fn)
                bb[fn] = ldsfrag(Bs, wn * 64 + fn * 16 + (lane & 15),
                                 kh * 64 + (lane >> 4) * 16);
#pragma unroll
            for (int fm = 0; fm < 4; ++fm)
#pragma unroll
                for (int fn = 0; fn < 4; ++fn)
                    acc[fm][fn] = __builtin_amdgcn_mfma_f32_16x16x32_f16(
                        a[fm], bb[fn], acc[fm][fn], 0, 0, 0);
        }
        __syncthreads();
    }

    const int lo4 = (lane >> 4) * 4, lp = lane & 15;
#pragma unroll
    for (int fm = 0; fm < 4; ++fm) {
#pragma unroll
        for (int fn = 0; fn < 4; ++fn) {
            const int c = m0 + wm * 64 + fm * 16 + lo4;
            const int q = n0 + wn * 64 + fn * 16 + lp;
#pragma unroll
            for (int r = 0; r < 4; ++r)
                Ob[(size_t)(c + r) * NP + q] = acc[fm][fn][r];
        }
    }
}

// ---------------------------------------------------------------------------
extern "C" void kernel_launch(void* const* d_in, const int* in_sizes, int n_in,
                              void* d_out, int out_size, void* d_ws, size_t ws_size,
                              hipStream_t stream)
{
    const float* f1  = (const float*)d_in[0];
    const float* f2  = (const float*)d_in[1];
    const float* Wq1 = (const float*)d_in[2];
    const float* bq1 = (const float*)d_in[3];
    const float* Wk1 = (const float*)d_in[4];
    const float* bk1 = (const float*)d_in[5];
    const float* Wq2 = (const float*)d_in[6];
    const float* bq2 = (const float*)d_in[7];
    const float* Wk2 = (const float*)d_in[8];
    const float* bk2 = (const float*)d_in[9];
    float* out = (float*)d_out;

    char* ws = (char*)d_ws;
    f16*   Ft   = (f16*)ws;                          // 67,108,864 B
    float* S    = (float*)ws;                        // reuse after proj
    f16*   attn = (f16*)(ws + 33554432);             // reuse
    f16*   QK   = (f16*)(ws + 67108864);             // 16,777,216 B
    f16*   Wf   = (f16*)(ws + 83886080);             //  4,194,304 B
    f16*   Vf   = (f16*)(ws + 88080384);             // 67,108,864 B

    const dim3 blk(256);

    convert_W<<<dim3(4 * CHID * CIN / 4 / 256), blk, 0, stream>>>(
        Wq1, Wk1, Wq2, Wk2, Wf);
    convert_F<<<dim3(NP / 64, CIN / 64, 2 * NB), blk, 0, stream>>>(f1, f2, Ft, Vf);

    proj_mfma<<<dim3(512), blk, 0, stream>>>(
        Wf, Ft, bq1, bk1, bq2, bk2, QK);

    for (int side = 0; side < 2; ++side) {
        scores_mfma<<<dim3(512), blk, 0, stream>>>(QK, S, side);
        softmax_rows<<<dim3(NB * NP), blk, 0, stream>>>(S, attn);
        // V for side0 is f2 (feat 1), side1 is f1 (feat 0)
        const f16* Vside = Vf + (size_t)(side ^ 1) * NB * CIN * NP;
        float* o = out + (size_t)side * NB * CIN * NP;
        attended_mfma<<<dim3(1024), blk, 0, stream>>>(Vside, attn, o);
    }
}